// Round 9
// baseline (270.575 us; speedup 1.0000x reference)
//
#include <hip/hip_runtime.h>
#include <hip/hip_bf16.h>
#include <math.h>

#define BATCH 2
#define CH 512
#define SEQ 4096
#define KDIM 256
#define VDIM 512
#define NHEADS 8
#define DK 32
#define DV 64

typedef unsigned short u16;
typedef unsigned int u32;
typedef __attribute__((ext_vector_type(8))) short bf16x8;
typedef __attribute__((ext_vector_type(4))) float f32x4;

__device__ __forceinline__ u16 f2bf(float f) {          // RNE (4 ops)
    u32 x = __float_as_uint(f);
    u32 r = (x + 0x7fffu + ((x >> 16) & 1u)) >> 16;
    return (u16)r;
}
__device__ __forceinline__ u16 f2bf_fast(float f) {     // half-up (2 ops)
    return (u16)((__float_as_uint(f) + 0x8000u) >> 16);
}
__device__ __forceinline__ u32 pack2f(float lo, float hi) {
    return (u32)f2bf_fast(lo) | (((__float_as_uint(hi) + 0x8000u) >> 16) << 16);
}

// ---------------------------------------------------------------------------
// Fused QKV projection, double-buffered LDS + register prefetch, ONE barrier
// per K-slab. Y[b][s][n] = scale * sum_c X[b][c][s] * W[c][n].
// Q is pre-scaled by 1/sqrt(dk)*log2(e) so attention can use exp2 directly.
// ---------------------------------------------------------------------------
__global__ __launch_bounds__(256) void qkv_proj(
    const float* __restrict__ X,
    const float* __restrict__ Wq, const float* __restrict__ Wk,
    const float* __restrict__ Wv,
    u16* __restrict__ Qh, u16* __restrict__ Kh, u16* __restrict__ Vh)
{
    __shared__ __align__(16) u16 Xs[2][64 * 40];
    __shared__ __align__(16) u16 Wsm[2][64 * 40];
    const int tid = threadIdx.x;
    const int w = tid >> 6, lane = tid & 63;
    const int c = lane & 15, quad = lane >> 4;
    const int s0 = blockIdx.x * 64, b = blockIdx.z;
    const int ny = blockIdx.y;

    // Q scale folded with log2(e) for exp2-domain attention
    const float QSCALE = 0.17677669529663687f * 1.4426950408889634f;
    const float* Wt; u16* Y; int N, n0; float scale;
    if (ny < 4)       { Wt = Wq; Y = Qh; N = KDIM; n0 = ny * 64;       scale = QSCALE; }
    else if (ny < 8)  { Wt = Wk; Y = Kh; N = KDIM; n0 = (ny - 4) * 64; scale = 1.0f; }
    else              { Wt = Wv; Y = Vh; N = VDIM; n0 = (ny - 8) * 64; scale = 1.0f; }

    const float* Xb = X + (size_t)b * CH * SEQ;
    const int cp = tid >> 4;         // c-pair index 0..15
    const int s4 = (tid & 15) * 4;   // s (or n) group of 4

    f32x4 acc[4];
#pragma unroll
    for (int g = 0; g < 4; ++g) acc[g] = (f32x4){0.f, 0.f, 0.f, 0.f};

    auto ldx = [&](int c0, float4& a, float4& bb) {
        a  = *reinterpret_cast<const float4*>(&Xb[(size_t)(c0 + 2 * cp) * SEQ + s0 + s4]);
        bb = *reinterpret_cast<const float4*>(&Xb[(size_t)(c0 + 2 * cp + 1) * SEQ + s0 + s4]);
    };
    auto ldw = [&](int c0, float4& a, float4& bb) {
        a  = *reinterpret_cast<const float4*>(&Wt[(size_t)(c0 + 2 * cp) * N + n0 + s4]);
        bb = *reinterpret_cast<const float4*>(&Wt[(size_t)(c0 + 2 * cp + 1) * N + n0 + s4]);
    };
    auto stage = [&](int buf, const float4& xa, const float4& xb,
                     const float4& wa, const float4& wb) {
        const float a[4] = {xa.x, xa.y, xa.z, xa.w};
        const float bb[4] = {xb.x, xb.y, xb.z, xb.w};
        const float aw[4] = {wa.x, wa.y, wa.z, wa.w};
        const float bw[4] = {wb.x, wb.y, wb.z, wb.w};
#pragma unroll
        for (int i = 0; i < 4; ++i) {
            *reinterpret_cast<u32*>(&Xs[buf][(s4 + i) * 40 + 2 * cp]) = pack2f(a[i], bb[i]);
            *reinterpret_cast<u32*>(&Wsm[buf][(s4 + i) * 40 + 2 * cp]) = pack2f(aw[i], bw[i]);
        }
    };

    float4 xa, xb, wa, wb;
    ldx(0, xa, xb); ldw(0, wa, wb);
    stage(0, xa, xb, wa, wb);
    ldx(32, xa, xb); ldw(32, wa, wb);

    for (int i = 0; i < 16; ++i) {
        const int cur = i & 1;
        __syncthreads();
        stage(cur ^ 1, xa, xb, wa, wb);          // slab i+1
        const int c0n = (i + 2 < 16) ? (i + 2) * 32 : 15 * 32;
        ldx(c0n, xa, xb); ldw(c0n, wa, wb);       // slab i+2 (clamped)
        const bf16x8 af = *reinterpret_cast<bf16x8*>(&Xs[cur][(w * 16 + c) * 40 + quad * 8]);
#pragma unroll
        for (int g = 0; g < 4; ++g) {
            bf16x8 bf_ = *reinterpret_cast<bf16x8*>(&Wsm[cur][(c + 16 * g) * 40 + quad * 8]);
            acc[g] = __builtin_amdgcn_mfma_f32_16x16x32_bf16(af, bf_, acc[g], 0, 0, 0);
        }
    }
    u16* Yb = Y + (size_t)b * SEQ * N;
#pragma unroll
    for (int r = 0; r < 4; ++r) {
        const int row = s0 + w * 16 + quad * 4 + r;
#pragma unroll
        for (int g = 0; g < 4; ++g)
            Yb[(size_t)row * N + n0 + c + 16 * g] = f2bf(acc[g][r] * scale);
    }
}

// ---------------------------------------------------------------------------
// MFMA causal flash attention v6: split-K pair + double-buffered LDS (ONE
// barrier/iter) + fused A/B tile processing (each K/V frag read ONCE per
// iteration and fed to both tiles' MFMAs) + exp2-domain softmax (Q carries
// the log2e factor). Fixed-max softmax -> additive partials -> LDS merge.
// Per-wave P strip round-trip relies on per-wave in-order DS execution.
// ---------------------------------------------------------------------------
__global__ __launch_bounds__(512, 4) void flash_mfma(
    const u16* __restrict__ Q, const u16* __restrict__ K,
    const u16* __restrict__ V, u16* __restrict__ AO)
{
    __shared__ __align__(16) union {
        struct {
            u16 Kl[2][2][64 * 40];   // [group][buf], K tile [n][k]
            u16 Vt[2][2][64 * 72];   // [group][buf], V^T tile [d][s]
            u16 Pl[8][16 * 72];      // per-wave P strip [m][k]
        } t;
        float mg[4][64][40];         // merge buffer
    } sh;

    const int tid  = threadIdx.x;
    const int w    = tid >> 6;      // 0..7
    const int ws   = w & 3;         // strip within group
    const int wg   = w >> 2;        // kb-parity group
    const int lane = tid & 63;
    const int c    = lane & 15;
    const int quad = lane >> 4;
    const int h = blockIdx.y, b = blockIdx.z;

    const int qbA = blockIdx.x;        // 0..31
    const int qbB = 63 - qbA;          // 32..63
    const int q0A = qbA * 64, q0B = qbB * 64;

    const u16* Qb = Q + (size_t)b * SEQ * KDIM + h * DK;
    const u16* Kb = K + (size_t)b * SEQ * KDIM + h * DK;
    const u16* Vb = V + (size_t)b * SEQ * VDIM + h * DV;
    u16* AOb = AO + (size_t)b * SEQ * VDIM + h * DV;

    const bf16x8 qfA = *reinterpret_cast<const bf16x8*>(
        &Qb[(size_t)(q0A + ws * 16 + c) * KDIM + quad * 8]);
    const bf16x8 qfB = *reinterpret_cast<const bf16x8*>(
        &Qb[(size_t)(q0B + ws * 16 + c) * KDIM + quad * 8]);

    f32x4 oA[4], oB[4];
#pragma unroll
    for (int g = 0; g < 4; ++g) {
        oA[g] = (f32x4){0.f, 0.f, 0.f, 0.f};
        oB[g] = (f32x4){0.f, 0.f, 0.f, 0.f};
    }
    float lA[4] = {0.f, 0.f, 0.f, 0.f}, lB[4] = {0.f, 0.f, 0.f, 0.f};

    const int t256 = tid & 255;
    const int krow = t256 >> 2, kc8 = (t256 & 3) * 8;
    const int vs0 = (t256 & 31) * 2, vd0 = (t256 >> 5) * 8;

    u16* const Plw = sh.t.Pl[w];
    const int T = (qbB >> 1) + 1;   // uniform trip count

    uint4 kreg, vra, vrb;
    auto ldtile = [&](int kb) {
        const int k0 = kb * 64;
        kreg = *reinterpret_cast<const uint4*>(&Kb[(size_t)(k0 + krow) * KDIM + kc8]);
        vra  = *reinterpret_cast<const uint4*>(&Vb[(size_t)(k0 + vs0) * VDIM + vd0]);
        vrb  = *reinterpret_cast<const uint4*>(&Vb[(size_t)(k0 + vs0 + 1) * VDIM + vd0]);
    };
    auto stagetile = [&](int buf) {
        *reinterpret_cast<uint4*>(&sh.t.Kl[wg][buf][krow * 40 + kc8]) = kreg;
        union { uint4 q; u16 s[8]; } ra, rb;
        ra.q = vra; rb.q = vrb;
#pragma unroll
        for (int i = 0; i < 8; ++i) {
            u32 packed = (u32)ra.s[i] | ((u32)rb.s[i] << 16);
            *reinterpret_cast<u32*>(&sh.t.Vt[wg][buf][(vd0 + i) * 72 + vs0]) = packed;
        }
    };

    ldtile(wg);                 // tile 0
    stagetile(0);
    ldtile(2 + wg);             // tile 1 (kb<=3, in-bounds)

    for (int it = 0; it < T; ++it) {
        const int kb = 2 * it + wg;
        const int k0 = kb * 64;
        const int cur = it & 1;
        __syncthreads();        // buf[cur] staged & prior reads of buf[cur^1] done
        stagetile(cur ^ 1);     // tile it+1
        {
            int kbn = 2 * (it + 2) + wg; if (kbn > 63) kbn = 63;
            ldtile(kbn);        // tile it+2 (clamped)
        }
        const u16* Klc = sh.t.Kl[wg][cur];
        const u16* Vtc = sh.t.Vt[wg][cur];
        const bool actA = (kb <= qbA);
        const bool actB = (kb <= qbB);

        // QK^T both tiles, each K frag read once
        f32x4 sA[4], sB[4];
#pragma unroll
        for (int g = 0; g < 4; ++g) {
            const bf16x8 kf = *reinterpret_cast<const bf16x8*>(&Klc[(c + 16 * g) * 40 + quad * 8]);
            const f32x4 z = {0.f, 0.f, 0.f, 0.f};
            if (actA) sA[g] = __builtin_amdgcn_mfma_f32_16x16x32_bf16(qfA, kf, z, 0, 0, 0);
            if (actB) sB[g] = __builtin_amdgcn_mfma_f32_16x16x32_bf16(qfB, kf, z, 0, 0, 0);
        }

        auto softmaxP = [&](f32x4* s, int q0, bool diag, float* l,
                            bf16x8& pa0, bf16x8& pa1) {
            if (diag) {
#pragma unroll
                for (int g = 0; g < 4; ++g) {
                    const int kcol = k0 + c + 16 * g;
#pragma unroll
                    for (int r = 0; r < 4; ++r) {
                        const int qr = q0 + ws * 16 + quad * 4 + r;
                        if (kcol > qr) s[g][r] = -1e30f;
                    }
                }
            }
            float p[4][4];
            float rs[4] = {0.f, 0.f, 0.f, 0.f};
#pragma unroll
            for (int g = 0; g < 4; ++g)
#pragma unroll
                for (int r = 0; r < 4; ++r) {
                    const float e = __builtin_amdgcn_exp2f(s[g][r]);
                    p[g][r] = e;
                    rs[r] += e;
                }
#pragma unroll
            for (int off = 1; off < 16; off <<= 1)
#pragma unroll
                for (int r = 0; r < 4; ++r)
                    rs[r] += __shfl_xor(rs[r], off);
#pragma unroll
            for (int r = 0; r < 4; ++r) l[r] += rs[r];
#pragma unroll
            for (int g = 0; g < 4; ++g)
#pragma unroll
                for (int r = 0; r < 4; ++r)
                    Plw[(quad * 4 + r) * 72 + c + 16 * g] = f2bf_fast(p[g][r]);
            pa0 = *reinterpret_cast<bf16x8*>(&Plw[c * 72 + quad * 8]);
            pa1 = *reinterpret_cast<bf16x8*>(&Plw[c * 72 + 32 + quad * 8]);
        };

        bf16x8 paA0, paA1, paB0, paB1;
        if (actA) softmaxP(sA, q0A, kb == qbA, lA, paA0, paA1);
        if (actB) softmaxP(sB, q0B, kb == qbB, lB, paB0, paB1);

        // PV both tiles, each V frag pair read once
#pragma unroll
        for (int g = 0; g < 4; ++g) {
            const bf16x8 v0 = *reinterpret_cast<const bf16x8*>(&Vtc[(c + 16 * g) * 72 + quad * 8]);
            const bf16x8 v1 = *reinterpret_cast<const bf16x8*>(&Vtc[(c + 16 * g) * 72 + 32 + quad * 8]);
            if (actA) {
                oA[g] = __builtin_amdgcn_mfma_f32_16x16x32_bf16(paA0, v0, oA[g], 0, 0, 0);
                oA[g] = __builtin_amdgcn_mfma_f32_16x16x32_bf16(paA1, v1, oA[g], 0, 0, 0);
            }
            if (actB) {
                oB[g] = __builtin_amdgcn_mfma_f32_16x16x32_bf16(paB0, v0, oB[g], 0, 0, 0);
                oB[g] = __builtin_amdgcn_mfma_f32_16x16x32_bf16(paB1, v1, oB[g], 0, 0, 0);
            }
        }
    }

    // ---- merge group 1 partials into group 0, then store ----
    __syncthreads();                 // all staging-LDS reads done; alias safe
    if (wg == 1) {
        float* m = sh.mg[ws][lane];
#pragma unroll
        for (int g = 0; g < 4; ++g)
#pragma unroll
            for (int r = 0; r < 4; ++r) {
                m[g * 4 + r]      = oA[g][r];
                m[16 + g * 4 + r] = oB[g][r];
            }
#pragma unroll
        for (int r = 0; r < 4; ++r) { m[32 + r] = lA[r]; m[36 + r] = lB[r]; }
    }
    __syncthreads();
    if (wg == 0) {
        const float* m = sh.mg[ws][lane];
#pragma unroll
        for (int g = 0; g < 4; ++g)
#pragma unroll
            for (int r = 0; r < 4; ++r) {
                oA[g][r] += m[g * 4 + r];
                oB[g][r] += m[16 + g * 4 + r];
            }
#pragma unroll
        for (int r = 0; r < 4; ++r) { lA[r] += m[32 + r]; lB[r] += m[36 + r]; }
#pragma unroll
        for (int r = 0; r < 4; ++r) {
            const float invA = 1.f / lA[r];
            const float invB = 1.f / lB[r];
            const int rowA = q0A + ws * 16 + quad * 4 + r;
            const int rowB = q0B + ws * 16 + quad * 4 + r;
#pragma unroll
            for (int g = 0; g < 4; ++g) {
                AOb[(size_t)rowA * VDIM + c + 16 * g] = f2bf(oA[g][r] * invA);
                AOb[(size_t)rowB * VDIM + c + 16 * g] = f2bf(oB[g][r] * invB);
            }
        }
    }
}

// ---------------------------------------------------------------------------
// MFMA output projection, double-buffered LDS + register prefetch, ONE
// barrier per K-slab. Out[m][n] = sum_k A[m][k] * Wo[k][n].
// ---------------------------------------------------------------------------
__global__ __launch_bounds__(256) void oproj_mfma(
    const u16* __restrict__ A, const float* __restrict__ Wo,
    float* __restrict__ Out)
{
    __shared__ __align__(16) u16 Ws[2][64 * 40];
    const int tid = threadIdx.x;
    const int w = tid >> 6, lane = tid & 63;
    const int c = lane & 15, quad = lane >> 4;
    const int m0 = blockIdx.x * 64, n0 = blockIdx.y * 64;
    const int kp = tid >> 4;         // k-pair index 0..15
    const int n4 = (tid & 15) * 4;   // n group of 4
    const u16* Arow = &A[(size_t)(m0 + w * 16 + c) * 512];

    f32x4 acc[4];
#pragma unroll
    for (int g = 0; g < 4; ++g) acc[g] = (f32x4){0.f, 0.f, 0.f, 0.f};

    auto ldw = [&](int k0, float4& a, float4& bb) {
        a  = *reinterpret_cast<const float4*>(&Wo[(size_t)(k0 + 2 * kp) * 512 + n0 + n4]);
        bb = *reinterpret_cast<const float4*>(&Wo[(size_t)(k0 + 2 * kp + 1) * 512 + n0 + n4]);
    };
    auto stage = [&](int buf, const float4& wa, const float4& wb) {
        const float a[4] = {wa.x, wa.y, wa.z, wa.w};
        const float bb[4] = {wb.x, wb.y, wb.z, wb.w};
#pragma unroll
        for (int i = 0; i < 4; ++i)
            *reinterpret_cast<u32*>(&Ws[buf][(n4 + i) * 40 + 2 * kp]) = pack2f(a[i], bb[i]);
    };

    float4 wa, wb;
    ldw(0, wa, wb);
    stage(0, wa, wb);
    ldw(32, wa, wb);
    bf16x8 afc = *reinterpret_cast<const bf16x8*>(&Arow[quad * 8]);

    for (int i = 0; i < 16; ++i) {
        const int cur = i & 1;
        __syncthreads();
        stage(cur ^ 1, wa, wb);                       // slab i+1
        const int k0n = (i + 2 < 16) ? (i + 2) * 32 : 15 * 32;
        ldw(k0n, wa, wb);                             // slab i+2 (clamped)
        const int k0a = (i + 1 < 16) ? (i + 1) * 32 : 15 * 32;
        const bf16x8 afn = *reinterpret_cast<const bf16x8*>(&Arow[k0a + quad * 8]);
#pragma unroll
        for (int g = 0; g < 4; ++g) {
            bf16x8 bf_ = *reinterpret_cast<bf16x8*>(&Ws[cur][(c + 16 * g) * 40 + quad * 8]);
            acc[g] = __builtin_amdgcn_mfma_f32_16x16x32_bf16(afc, bf_, acc[g], 0, 0, 0);
        }
        afc = afn;
    }
#pragma unroll
    for (int r = 0; r < 4; ++r) {
        const int row = m0 + w * 16 + quad * 4 + r;
#pragma unroll
        for (int g = 0; g < 4; ++g)
            Out[(size_t)row * 512 + n0 + c + 16 * g] = acc[g][r];
    }
}

extern "C" void kernel_launch(void* const* d_in, const int* in_sizes, int n_in,
                              void* d_out, int out_size, void* d_ws, size_t ws_size,
                              hipStream_t stream) {
    const float* X  = (const float*)d_in[0];
    const float* Wq = (const float*)d_in[1];
    const float* Wk = (const float*)d_in[2];
    const float* Wv = (const float*)d_in[3];
    const float* Wo = (const float*)d_in[4];
    float* out = (float*)d_out;

    // bf16 workspace: 24 MB total
    const size_t qk = (size_t)BATCH * SEQ * KDIM;
    const size_t vs = (size_t)BATCH * SEQ * VDIM;
    u16* Qh  = (u16*)d_ws;        // [B][SEQ][KDIM]  4 MB
    u16* Kh  = Qh + qk;           // [B][SEQ][KDIM]  4 MB
    u16* Vh  = Kh + qk;           // [B][SEQ][VDIM]  8 MB
    u16* AOh = Vh + vs;           // [B][SEQ][VDIM]  8 MB

    qkv_proj<<<dim3(SEQ / 64, 16, BATCH), 256, 0, stream>>>(
        X, Wq, Wk, Wv, Qh, Kh, Vh);
    flash_mfma<<<dim3(32, NHEADS, BATCH), 512, 0, stream>>>(Qh, Kh, Vh, AOh);
    oproj_mfma<<<dim3((BATCH * SEQ) / 64, VDIM / 64), 256, 0, stream>>>(AOh, Wo, out);
}

// Round 10
// 209.552 us; speedup vs baseline: 1.2912x; 1.2912x over previous
//
#include <hip/hip_runtime.h>
#include <hip/hip_bf16.h>
#include <math.h>

#define BATCH 2
#define CH 512
#define SEQ 4096
#define KDIM 256
#define VDIM 512
#define NHEADS 8
#define DK 32
#define DV 64

typedef unsigned short u16;
typedef unsigned int u32;
typedef __attribute__((ext_vector_type(8))) short bf16x8;
typedef __attribute__((ext_vector_type(4))) float f32x4;

__device__ __forceinline__ u16 f2bf(float f) {          // RNE (4 ops)
    u32 x = __float_as_uint(f);
    u32 r = (x + 0x7fffu + ((x >> 16) & 1u)) >> 16;
    return (u16)r;
}
__device__ __forceinline__ u16 f2bf_fast(float f) {     // half-up (2 ops)
    return (u16)((__float_as_uint(f) + 0x8000u) >> 16);
}
__device__ __forceinline__ u32 pack2f(float lo, float hi) {
    return (u32)f2bf_fast(lo) | (((__float_as_uint(hi) + 0x8000u) >> 16) << 16);
}

// ---------------------------------------------------------------------------
// Fused QKV projection, double-buffered LDS + register prefetch, ONE barrier
// per K-slab. Y[b][s][n] = scale * sum_c X[b][c][s] * W[c][n].
// Q is pre-scaled by 1/sqrt(dk)*log2(e) so attention can use exp2 directly.
// ---------------------------------------------------------------------------
__global__ __launch_bounds__(256) void qkv_proj(
    const float* __restrict__ X,
    const float* __restrict__ Wq, const float* __restrict__ Wk,
    const float* __restrict__ Wv,
    u16* __restrict__ Qh, u16* __restrict__ Kh, u16* __restrict__ Vh)
{
    __shared__ __align__(16) u16 Xs[2][64 * 40];
    __shared__ __align__(16) u16 Wsm[2][64 * 40];
    const int tid = threadIdx.x;
    const int w = tid >> 6, lane = tid & 63;
    const int c = lane & 15, quad = lane >> 4;
    const int s0 = blockIdx.x * 64, b = blockIdx.z;
    const int ny = blockIdx.y;

    // Q scale folded with log2(e) for exp2-domain attention
    const float QSCALE = 0.17677669529663687f * 1.4426950408889634f;
    const float* Wt; u16* Y; int N, n0; float scale;
    if (ny < 4)       { Wt = Wq; Y = Qh; N = KDIM; n0 = ny * 64;       scale = QSCALE; }
    else if (ny < 8)  { Wt = Wk; Y = Kh; N = KDIM; n0 = (ny - 4) * 64; scale = 1.0f; }
    else              { Wt = Wv; Y = Vh; N = VDIM; n0 = (ny - 8) * 64; scale = 1.0f; }

    const float* Xb = X + (size_t)b * CH * SEQ;
    const int cp = tid >> 4;         // c-pair index 0..15
    const int s4 = (tid & 15) * 4;   // s (or n) group of 4

    f32x4 acc[4];
#pragma unroll
    for (int g = 0; g < 4; ++g) acc[g] = (f32x4){0.f, 0.f, 0.f, 0.f};

    auto ldx = [&](int c0, float4& a, float4& bb) {
        a  = *reinterpret_cast<const float4*>(&Xb[(size_t)(c0 + 2 * cp) * SEQ + s0 + s4]);
        bb = *reinterpret_cast<const float4*>(&Xb[(size_t)(c0 + 2 * cp + 1) * SEQ + s0 + s4]);
    };
    auto ldw = [&](int c0, float4& a, float4& bb) {
        a  = *reinterpret_cast<const float4*>(&Wt[(size_t)(c0 + 2 * cp) * N + n0 + s4]);
        bb = *reinterpret_cast<const float4*>(&Wt[(size_t)(c0 + 2 * cp + 1) * N + n0 + s4]);
    };
    auto stage = [&](int buf, const float4& xa, const float4& xb,
                     const float4& wa, const float4& wb) {
        const float a[4] = {xa.x, xa.y, xa.z, xa.w};
        const float bb[4] = {xb.x, xb.y, xb.z, xb.w};
        const float aw[4] = {wa.x, wa.y, wa.z, wa.w};
        const float bw[4] = {wb.x, wb.y, wb.z, wb.w};
#pragma unroll
        for (int i = 0; i < 4; ++i) {
            *reinterpret_cast<u32*>(&Xs[buf][(s4 + i) * 40 + 2 * cp]) = pack2f(a[i], bb[i]);
            *reinterpret_cast<u32*>(&Wsm[buf][(s4 + i) * 40 + 2 * cp]) = pack2f(aw[i], bw[i]);
        }
    };

    float4 xa, xb, wa, wb;
    ldx(0, xa, xb); ldw(0, wa, wb);
    stage(0, xa, xb, wa, wb);
    ldx(32, xa, xb); ldw(32, wa, wb);

    for (int i = 0; i < 16; ++i) {
        const int cur = i & 1;
        __syncthreads();
        stage(cur ^ 1, xa, xb, wa, wb);          // slab i+1
        const int c0n = (i + 2 < 16) ? (i + 2) * 32 : 15 * 32;
        ldx(c0n, xa, xb); ldw(c0n, wa, wb);       // slab i+2 (clamped)
        const bf16x8 af = *reinterpret_cast<bf16x8*>(&Xs[cur][(w * 16 + c) * 40 + quad * 8]);
#pragma unroll
        for (int g = 0; g < 4; ++g) {
            bf16x8 bf_ = *reinterpret_cast<bf16x8*>(&Wsm[cur][(c + 16 * g) * 40 + quad * 8]);
            acc[g] = __builtin_amdgcn_mfma_f32_16x16x32_bf16(af, bf_, acc[g], 0, 0, 0);
        }
    }
    u16* Yb = Y + (size_t)b * SEQ * N;
#pragma unroll
    for (int r = 0; r < 4; ++r) {
        const int row = s0 + w * 16 + quad * 4 + r;
#pragma unroll
        for (int g = 0; g < 4; ++g)
            Yb[(size_t)row * N + n0 + c + 16 * g] = f2bf(acc[g][r] * scale);
    }
}

// ---------------------------------------------------------------------------
// MFMA causal flash attention v7: split-K pair + double-buffered LDS (ONE
// barrier/iter) + SEQUENTIAL per-tile compute (registers reused between tile
// A and tile B -> no spill; round-9's fused variant spilled: VGPR capped 64,
// 161 MB scratch writes) + exp2-domain softmax (Q carries log2e).
// Fixed-max softmax -> additive partials -> LDS merge.
// ---------------------------------------------------------------------------
__global__ __launch_bounds__(512, 4) void flash_mfma(
    const u16* __restrict__ Q, const u16* __restrict__ K,
    const u16* __restrict__ V, u16* __restrict__ AO)
{
    __shared__ __align__(16) union {
        struct {
            u16 Kl[2][2][64 * 40];   // [group][buf], K tile [n][k]
            u16 Vt[2][2][64 * 72];   // [group][buf], V^T tile [d][s]
            u16 Pl[8][16 * 72];      // per-wave P strip [m][k]
        } t;
        float mg[4][64][40];         // merge buffer
    } sh;

    const int tid  = threadIdx.x;
    const int w    = tid >> 6;      // 0..7
    const int ws   = w & 3;         // strip within group
    const int wg   = w >> 2;        // kb-parity group
    const int lane = tid & 63;
    const int c    = lane & 15;
    const int quad = lane >> 4;
    const int h = blockIdx.y, b = blockIdx.z;

    const int qbA = blockIdx.x;        // 0..31
    const int qbB = 63 - qbA;          // 32..63
    const int q0A = qbA * 64, q0B = qbB * 64;

    const u16* Qb = Q + (size_t)b * SEQ * KDIM + h * DK;
    const u16* Kb = K + (size_t)b * SEQ * KDIM + h * DK;
    const u16* Vb = V + (size_t)b * SEQ * VDIM + h * DV;
    u16* AOb = AO + (size_t)b * SEQ * VDIM + h * DV;

    const bf16x8 qfA = *reinterpret_cast<const bf16x8*>(
        &Qb[(size_t)(q0A + ws * 16 + c) * KDIM + quad * 8]);
    const bf16x8 qfB = *reinterpret_cast<const bf16x8*>(
        &Qb[(size_t)(q0B + ws * 16 + c) * KDIM + quad * 8]);

    f32x4 oA[4], oB[4];
#pragma unroll
    for (int g = 0; g < 4; ++g) {
        oA[g] = (f32x4){0.f, 0.f, 0.f, 0.f};
        oB[g] = (f32x4){0.f, 0.f, 0.f, 0.f};
    }
    float lA[4] = {0.f, 0.f, 0.f, 0.f}, lB[4] = {0.f, 0.f, 0.f, 0.f};

    const int t256 = tid & 255;
    const int krow = t256 >> 2, kc8 = (t256 & 3) * 8;
    const int vs0 = (t256 & 31) * 2, vd0 = (t256 >> 5) * 8;

    u16* const Plw = sh.t.Pl[w];
    const int T = (qbB >> 1) + 1;   // uniform trip count

    uint4 kreg, vra, vrb;
    auto ldtile = [&](int kb) {
        const int k0 = kb * 64;
        kreg = *reinterpret_cast<const uint4*>(&Kb[(size_t)(k0 + krow) * KDIM + kc8]);
        vra  = *reinterpret_cast<const uint4*>(&Vb[(size_t)(k0 + vs0) * VDIM + vd0]);
        vrb  = *reinterpret_cast<const uint4*>(&Vb[(size_t)(k0 + vs0 + 1) * VDIM + vd0]);
    };
    auto stagetile = [&](int buf) {
        *reinterpret_cast<uint4*>(&sh.t.Kl[wg][buf][krow * 40 + kc8]) = kreg;
        union { uint4 q; u16 s[8]; } ra, rb;
        ra.q = vra; rb.q = vrb;
#pragma unroll
        for (int i = 0; i < 8; ++i) {
            u32 packed = (u32)ra.s[i] | ((u32)rb.s[i] << 16);
            *reinterpret_cast<u32*>(&sh.t.Vt[wg][buf][(vd0 + i) * 72 + vs0]) = packed;
        }
    };

    ldtile(wg);                 // tile 0
    stagetile(0);
    ldtile(2 + wg);             // tile 1

    for (int it = 0; it < T; ++it) {
        const int kb = 2 * it + wg;
        const int k0 = kb * 64;
        const int cur = it & 1;
        __syncthreads();        // buf[cur] staged by all; buf[cur^1] reads done
        stagetile(cur ^ 1);     // tile it+1 from regs
        {
            int kbn = 2 * (it + 2) + wg; if (kbn > 63) kbn = 63;
            ldtile(kbn);        // tile it+2 (clamped)
        }
        const u16* Klc = sh.t.Kl[wg][cur];
        const u16* Vtc = sh.t.Vt[wg][cur];

        // sequential per-tile compute: registers reused between A and B
        auto compute = [&](const bf16x8& qf, int q0, bool diag,
                           f32x4* o, float* l) {
            f32x4 s[4];
#pragma unroll
            for (int g = 0; g < 4; ++g) {
                const bf16x8 kf = *reinterpret_cast<const bf16x8*>(
                    &Klc[(c + 16 * g) * 40 + quad * 8]);
                const f32x4 z = {0.f, 0.f, 0.f, 0.f};
                s[g] = __builtin_amdgcn_mfma_f32_16x16x32_bf16(qf, kf, z, 0, 0, 0);
            }
            if (diag) {
#pragma unroll
                for (int g = 0; g < 4; ++g) {
                    const int kcol = k0 + c + 16 * g;
#pragma unroll
                    for (int r = 0; r < 4; ++r) {
                        const int qr = q0 + ws * 16 + quad * 4 + r;
                        if (kcol > qr) s[g][r] = -1e30f;
                    }
                }
            }
            float p[4][4];
            float rs[4] = {0.f, 0.f, 0.f, 0.f};
#pragma unroll
            for (int g = 0; g < 4; ++g)
#pragma unroll
                for (int r = 0; r < 4; ++r) {
                    const float e = __builtin_amdgcn_exp2f(s[g][r]);
                    p[g][r] = e;
                    rs[r] += e;
                }
#pragma unroll
            for (int off = 1; off < 16; off <<= 1)
#pragma unroll
                for (int r = 0; r < 4; ++r)
                    rs[r] += __shfl_xor(rs[r], off);
#pragma unroll
            for (int r = 0; r < 4; ++r) l[r] += rs[r];
            // P: C-layout -> own wave's LDS strip -> A-layout (no barrier)
#pragma unroll
            for (int g = 0; g < 4; ++g)
#pragma unroll
                for (int r = 0; r < 4; ++r)
                    Plw[(quad * 4 + r) * 72 + c + 16 * g] = f2bf_fast(p[g][r]);
            const bf16x8 pa0 = *reinterpret_cast<bf16x8*>(&Plw[c * 72 + quad * 8]);
            const bf16x8 pa1 = *reinterpret_cast<bf16x8*>(&Plw[c * 72 + 32 + quad * 8]);
#pragma unroll
            for (int g = 0; g < 4; ++g) {
                const bf16x8 v0 = *reinterpret_cast<const bf16x8*>(
                    &Vtc[(c + 16 * g) * 72 + quad * 8]);
                const bf16x8 v1 = *reinterpret_cast<const bf16x8*>(
                    &Vtc[(c + 16 * g) * 72 + 32 + quad * 8]);
                o[g] = __builtin_amdgcn_mfma_f32_16x16x32_bf16(pa0, v0, o[g], 0, 0, 0);
                o[g] = __builtin_amdgcn_mfma_f32_16x16x32_bf16(pa1, v1, o[g], 0, 0, 0);
            }
        };

        if (kb <= qbA) compute(qfA, q0A, kb == qbA, oA, lA);
        if (kb <= qbB) compute(qfB, q0B, kb == qbB, oB, lB);
    }

    // ---- merge group 1 partials into group 0, then store ----
    __syncthreads();                 // all staging-LDS reads done; alias safe
    if (wg == 1) {
        float* m = sh.mg[ws][lane];
#pragma unroll
        for (int g = 0; g < 4; ++g)
#pragma unroll
            for (int r = 0; r < 4; ++r) {
                m[g * 4 + r]      = oA[g][r];
                m[16 + g * 4 + r] = oB[g][r];
            }
#pragma unroll
        for (int r = 0; r < 4; ++r) { m[32 + r] = lA[r]; m[36 + r] = lB[r]; }
    }
    __syncthreads();
    if (wg == 0) {
        const float* m = sh.mg[ws][lane];
#pragma unroll
        for (int g = 0; g < 4; ++g)
#pragma unroll
            for (int r = 0; r < 4; ++r) {
                oA[g][r] += m[g * 4 + r];
                oB[g][r] += m[16 + g * 4 + r];
            }
#pragma unroll
        for (int r = 0; r < 4; ++r) { lA[r] += m[32 + r]; lB[r] += m[36 + r]; }
#pragma unroll
        for (int r = 0; r < 4; ++r) {
            const float invA = 1.f / lA[r];
            const float invB = 1.f / lB[r];
            const int rowA = q0A + ws * 16 + quad * 4 + r;
            const int rowB = q0B + ws * 16 + quad * 4 + r;
#pragma unroll
            for (int g = 0; g < 4; ++g) {
                AOb[(size_t)rowA * VDIM + c + 16 * g] = f2bf(oA[g][r] * invA);
                AOb[(size_t)rowB * VDIM + c + 16 * g] = f2bf(oB[g][r] * invB);
            }
        }
    }
}

// ---------------------------------------------------------------------------
// MFMA output projection, double-buffered LDS + register prefetch, ONE
// barrier per K-slab. Out[m][n] = sum_k A[m][k] * Wo[k][n].
// ---------------------------------------------------------------------------
__global__ __launch_bounds__(256) void oproj_mfma(
    const u16* __restrict__ A, const float* __restrict__ Wo,
    float* __restrict__ Out)
{
    __shared__ __align__(16) u16 Ws[2][64 * 40];
    const int tid = threadIdx.x;
    const int w = tid >> 6, lane = tid & 63;
    const int c = lane & 15, quad = lane >> 4;
    const int m0 = blockIdx.x * 64, n0 = blockIdx.y * 64;
    const int kp = tid >> 4;         // k-pair index 0..15
    const int n4 = (tid & 15) * 4;   // n group of 4
    const u16* Arow = &A[(size_t)(m0 + w * 16 + c) * 512];

    f32x4 acc[4];
#pragma unroll
    for (int g = 0; g < 4; ++g) acc[g] = (f32x4){0.f, 0.f, 0.f, 0.f};

    auto ldw = [&](int k0, float4& a, float4& bb) {
        a  = *reinterpret_cast<const float4*>(&Wo[(size_t)(k0 + 2 * kp) * 512 + n0 + n4]);
        bb = *reinterpret_cast<const float4*>(&Wo[(size_t)(k0 + 2 * kp + 1) * 512 + n0 + n4]);
    };
    auto stage = [&](int buf, const float4& wa, const float4& wb) {
        const float a[4] = {wa.x, wa.y, wa.z, wa.w};
        const float bb[4] = {wb.x, wb.y, wb.z, wb.w};
#pragma unroll
        for (int i = 0; i < 4; ++i)
            *reinterpret_cast<u32*>(&Ws[buf][(n4 + i) * 40 + 2 * kp]) = pack2f(a[i], bb[i]);
    };

    float4 wa, wb;
    ldw(0, wa, wb);
    stage(0, wa, wb);
    ldw(32, wa, wb);
    bf16x8 afc = *reinterpret_cast<const bf16x8*>(&Arow[quad * 8]);

    for (int i = 0; i < 16; ++i) {
        const int cur = i & 1;
        __syncthreads();
        stage(cur ^ 1, wa, wb);                       // slab i+1
        const int k0n = (i + 2 < 16) ? (i + 2) * 32 : 15 * 32;
        ldw(k0n, wa, wb);                             // slab i+2 (clamped)
        const int k0a = (i + 1 < 16) ? (i + 1) * 32 : 15 * 32;
        const bf16x8 afn = *reinterpret_cast<const bf16x8*>(&Arow[k0a + quad * 8]);
#pragma unroll
        for (int g = 0; g < 4; ++g) {
            bf16x8 bf_ = *reinterpret_cast<bf16x8*>(&Ws[cur][(c + 16 * g) * 40 + quad * 8]);
            acc[g] = __builtin_amdgcn_mfma_f32_16x16x32_bf16(afc, bf_, acc[g], 0, 0, 0);
        }
        afc = afn;
    }
#pragma unroll
    for (int r = 0; r < 4; ++r) {
        const int row = m0 + w * 16 + quad * 4 + r;
#pragma unroll
        for (int g = 0; g < 4; ++g)
            Out[(size_t)row * 512 + n0 + c + 16 * g] = acc[g][r];
    }
}

extern "C" void kernel_launch(void* const* d_in, const int* in_sizes, int n_in,
                              void* d_out, int out_size, void* d_ws, size_t ws_size,
                              hipStream_t stream) {
    const float* X  = (const float*)d_in[0];
    const float* Wq = (const float*)d_in[1];
    const float* Wk = (const float*)d_in[2];
    const float* Wv = (const float*)d_in[3];
    const float* Wo = (const float*)d_in[4];
    float* out = (float*)d_out;

    // bf16 workspace: 24 MB total
    const size_t qk = (size_t)BATCH * SEQ * KDIM;
    const size_t vs = (size_t)BATCH * SEQ * VDIM;
    u16* Qh  = (u16*)d_ws;        // [B][SEQ][KDIM]  4 MB
    u16* Kh  = Qh + qk;           // [B][SEQ][KDIM]  4 MB
    u16* Vh  = Kh + qk;           // [B][SEQ][VDIM]  8 MB
    u16* AOh = Vh + vs;           // [B][SEQ][VDIM]  8 MB

    qkv_proj<<<dim3(SEQ / 64, 16, BATCH), 256, 0, stream>>>(
        X, Wq, Wk, Wv, Qh, Kh, Vh);
    flash_mfma<<<dim3(32, NHEADS, BATCH), 512, 0, stream>>>(Qh, Kh, Vh, AOh);
    oproj_mfma<<<dim3((BATCH * SEQ) / 64, VDIM / 64), 256, 0, stream>>>(AOh, Wo, out);
}